// Round 8
// baseline (70.095 us; speedup 1.0000x reference)
//
#include <hip/hip_runtime.h>

// AffinitySideLoss: B=4, E=12, H=W=512, S=8 offsets, output = 1 float scalar.
// d_in[0] = input_ float32 [4,12,512,512]
// d_in[1] = target int32   [4,1,512,512]
// d_in[2] = offsets int32  [8,2]  (values in [-27,0))
// d_out   = float32 [1]
// d_ws    = per-block partials: float [16][512]
//
// R8: 2D supertile + LDS halo reuse. Block = 32x64-px tile (1024 thr, 2 px
// each). Per channel, the 60x92 halo (rows r0-28..r0+31, cols c0-28..c0+63)
// is staged ONCE into LDS; all 9 emb reads/px/channel hit LDS. Unique-line
// L2 demand drops ~2.9x vs the 9x-refetch kernels (R4-R7 all pinned at
// ~45us by per-CU miss throughput). Triple-buffered staging so the
// compiler's vmcnt(0)-before-barrier drain lands after a compute phase.

typedef float f2 __attribute__((ext_vector_type(2)));
typedef int   i2 __attribute__((ext_vector_type(2)));

#define HWSZ  262144     // 512*512
#define NE    12
#define NS    8
#define NBLK  512        // 4 batches x 16 tile_y x 8 tile_x
#define TROWS 32
#define TCOLS 64
#define HROWS 60         // TROWS + 28 (halo above, rounded for alignment)
#define HCOLS 92         // TCOLS + 28
#define HSZ   (HROWS * HCOLS)   // 5520 floats
#define HSLOTS (HSZ / 4)        // 1380 16B slots

typedef const __attribute__((address_space(1))) void* gas_t;
typedef __attribute__((address_space(3))) void* las_t;

__global__ __launch_bounds__(1024, 8) void affloss_main(
    const float* __restrict__ emb, const int* __restrict__ seg,
    const int* __restrict__ offs, float* __restrict__ partial) {
  __shared__ float lbuf[3][HSZ];   // 3 x 22080 B = 66240 B
  __shared__ float red[16][16];

  // XCD swizzle (bijective, 512 % 8 == 0): each XCD gets 64 consecutive nb
  // = a contiguous half-batch of tiles -> neighbor-tile halo overlap (28 of
  // 60 rows / 28 of 92 cols) hits that XCD's L2.
  const int bid = blockIdx.x;
  const int nb  = (bid & 7) * (NBLK / 8) + (bid >> 3);
  const int b   = nb >> 7;                 // batch 0..3
  const int rem = nb & 127;
  const int r0  = (rem >> 3) * TROWS;      // 0..480
  const int c0  = (rem & 7) * TCOLS;       // 0..448

  const int tid = threadIdx.x;
  const int ty  = tid >> 5;                // 0..31
  const int tx  = tid & 31;                // px cols c0+2tx, c0+2tx+1

  const float* embB = emb + (size_t)b * NE * HWSZ;
  const int*   segB = seg + (size_t)b * HWSZ;

  // offsets: uniform-address reads -> scalar; oy,ox in [-27,-1]
  int oyv[NS], oxv[NS], soff[NS];
  #pragma unroll
  for (int s = 0; s < NS; ++s) {
    oyv[s] = offs[2 * s];
    oxv[s] = offs[2 * s + 1];
    soff[s] = oyv[s] * HCOLS + oxv[s];
  }

  const bool interior = (r0 >= 28) && (c0 >= 28);  // no clamping in halo

  // Stage channel e's 60x92 halo into lbuf[k].
  // LDS[r][c] = img[clamp(r0-28+r)][clamp(c0-28+c)] (clamp = replication pad).
  // Interior: 16B slots, slot i -> row i/23, cols 4*(i%23).. (92 = 23*4, so
  // no slot crosses a row). Source 16B-aligned: (c0-28)*4 % 16 == 0.
  // Edge: width-4 with per-lane clamped addresses.
  auto stage = [&](int k, int e) {
    float* dst = lbuf[k];
    const float* srcB = embB + e * HWSZ;
    if (interior) {
      {
        const unsigned i0 = tid;
        const unsigned r_ = i0 / 23u, cs = i0 - r_ * 23u;
        const float* src = srcB + (r0 - 28 + (int)r_) * 512 + (c0 - 28 + 4 * (int)cs);
        __builtin_amdgcn_global_load_lds((gas_t)src, (las_t)(dst + i0 * 4), 16, 0, 0);
      }
      if (tid < HSLOTS - 1024) {   // 356 remaining slots
        const unsigned i1 = tid + 1024;
        const unsigned r_ = i1 / 23u, cs = i1 - r_ * 23u;
        const float* src = srcB + (r0 - 28 + (int)r_) * 512 + (c0 - 28 + 4 * (int)cs);
        __builtin_amdgcn_global_load_lds((gas_t)src, (las_t)(dst + i1 * 4), 16, 0, 0);
      }
    } else {
      #pragma unroll
      for (int k6 = 0; k6 < 6; ++k6) {
        const unsigned f = tid + k6 * 1024;
        if (f < HSZ) {
          const unsigned r_ = f / 92u, c_ = f - r_ * 92u;
          int gr = r0 - 28 + (int)r_; gr = gr < 0 ? 0 : gr;   // upper never exceeds 511
          int gc = c0 - 28 + (int)c_; gc = gc < 0 ? 0 : gc;
          __builtin_amdgcn_global_load_lds((gas_t)(srcB + gr * 512 + gc),
                                           (las_t)(dst + f), 4, 0, 0);
        }
      }
    }
  };

  f2 ssv[NS];
  #pragma unroll
  for (int s = 0; s < NS; ++s) ssv[s] = f2{0.f, 0.f};

  const int cbase = (ty + 28) * HCOLS + 28 + 2 * tx;   // center px0 float idx

  stage(0, 0);
  stage(1, 1);

  #pragma unroll 3
  for (int e = 0; e < NE; ++e) {
    __syncthreads();            // drains vmcnt: buf[e%3] ready; readers of buf[(e+2)%3] done
    if (e + 2 < NE) stage((e + 2) % 3, e + 2);   // flies during compute below

    const float* buf = lbuf[e % 3];
    const f2 cc = *reinterpret_cast<const f2*>(buf + cbase);   // 8B-aligned
    #pragma unroll
    for (int s = 0; s < NS; ++s) {
      const int a = cbase + soff[s];   // row in [1,58], col in [1,90] -> in halo
      f2 sh;
      if (oxv[s] & 1) {                // wave-uniform branch; odd ox: 2x b32
        sh[0] = buf[a];
        sh[1] = buf[a + 1];
      } else {                         // even ox: aligned b64
        sh = *reinterpret_cast<const f2*>(buf + a);
      }
      const f2 d = cc - sh;
      ssv[s][0] = fmaf(d[0], d[0], ssv[s][0]);
      ssv[s][1] = fmaf(d[1], d[1], ssv[s][1]);
    }
  }

  // Epilogue: seg affinities (L2-hot direct loads) + dice partials.
  const int r = r0 + ty, c = c0 + 2 * tx;
  const i2 tc = *reinterpret_cast<const i2*>(segB + r * 512 + c);
  float arr[16];                        // [0..7]=num, [8..15]=den
  #pragma unroll
  for (int s = 0; s < NS; ++s) {
    int sr = r + oyv[s]; sr = sr < 0 ? 0 : sr;
    const int sc = c + oxv[s];
    const int w0 = sc < 0 ? 0 : sc;
    const int w1 = sc + 1 < 0 ? 0 : sc + 1;
    const int* ps = segB + sr * 512;
    const int t0 = ps[w0], t1 = ps[w1];

    float nacc = 0.f, dacc = 0.f;
    {
      const float n = __builtin_amdgcn_sqrtf(ssv[s][0]);
      const float rr = fmaxf(fmaf(n, -(1.0f / 3.0f), 1.0f), 0.0f);
      const float a = fmaf(-rr, rr, 1.0f);
      const float ta = (tc[0] == t0) ? 0.f : 1.f;
      nacc = fmaf(a, ta, nacc); dacc += fmaf(a, a, ta);
    }
    {
      const float n = __builtin_amdgcn_sqrtf(ssv[s][1]);
      const float rr = fmaxf(fmaf(n, -(1.0f / 3.0f), 1.0f), 0.0f);
      const float a = fmaf(-rr, rr, 1.0f);
      const float ta = (tc[1] == t1) ? 0.f : 1.f;
      nacc = fmaf(a, ta, nacc); dacc += fmaf(a, a, ta);
    }
    arr[s] = nacc;
    arr[8 + s] = dacc;
  }

  // wave shuffle reduction (16 waves) -> LDS -> 16 partials per block
  #pragma unroll
  for (int k = 0; k < 16; ++k) {
    float v = arr[k];
    #pragma unroll
    for (int o = 32; o > 0; o >>= 1) v += __shfl_down(v, o, 64);
    arr[k] = v;
  }
  const int lane = tid & 63, wv = tid >> 6;
  if (lane == 0) {
    #pragma unroll
    for (int k = 0; k < 16; ++k) red[wv][k] = arr[k];
  }
  __syncthreads();
  if (tid < 16) {
    float v = 0.f;
    #pragma unroll
    for (int w = 0; w < 16; ++w) v += red[w][tid];
    partial[tid * NBLK + blockIdx.x] = v;   // [channel][block]
  }
}

__global__ __launch_bounds__(1024) void affloss_final(
    const float* __restrict__ partial, float* __restrict__ out) {
  __shared__ double csum[16];
  const int lane = threadIdx.x & 63, wv = threadIdx.x >> 6;  // wv = channel

  double s = 0.0;
  for (int i = lane; i < NBLK; i += 64)
    s += (double)partial[wv * NBLK + i];
  #pragma unroll
  for (int o = 32; o > 0; o >>= 1) s += __shfl_down(s, o, 64);
  if (lane == 0) csum[wv] = s;
  __syncthreads();

  if (threadIdx.x == 0) {
    double total = 0.0;
    #pragma unroll
    for (int c = 0; c < 8; ++c) {
      double num = csum[c];
      double den = csum[8 + c];
      if (den < 1e-7) den = 1e-7;            // maximum(den, EPS)
      total += 1.0 - 2.0 * num / den;
    }
    out[0] = (float)total;
  }
}

extern "C" void kernel_launch(void* const* d_in, const int* in_sizes, int n_in,
                              void* d_out, int out_size, void* d_ws, size_t ws_size,
                              hipStream_t stream) {
  const float* emb  = (const float*)d_in[0];
  const int*   seg  = (const int*)d_in[1];
  const int*   offs = (const int*)d_in[2];
  float* partial = (float*)d_ws;   // 16*512 floats = 32,768 B

  affloss_main<<<NBLK, 1024, 0, stream>>>(emb, seg, offs, partial);
  affloss_final<<<1, 1024, 0, stream>>>(partial, (float*)d_out);
}

// Round 9
// 41.879 us; speedup vs baseline: 1.6737x; 1.6737x over previous
//
#include <hip/hip_runtime.h>

// AffinitySideLoss: B=4, E=12, H=W=512, S=8 offsets, output = 1 float scalar.
// d_in[0] = input_ float32 [4,12,512,512]
// d_in[1] = target int32   [4,1,512,512]
// d_in[2] = offsets int32  [8,2]  (values in [-27,0))
// d_out   = float32 [1]
// d_ws    = per-block partials: float [16][512]  (32 KB)
//
// R9: 16x128 supertile, single-LDS-buffer halo reuse, REG-STAGED staging
// (plain f4 loads -> ds_write_b128; global_load_lds proved to bypass the
// Infinity Cache in R6/R8 -> HBM latency on the critical path). Each of 13
// channels (12 emb + seg-as-bits) stages a 44x156 halo once; all 9
// reads/px/channel then hit LDS. L2 demand: 183 MB vs 490 MB for the
// direct-load kernels (all pinned at ~45us by ~18 B/cyc/CU L2 delivery).
// Wave = one full 128-col row -> contiguous-lane LDS reads.

typedef float f2 __attribute__((ext_vector_type(2)));
typedef float f4 __attribute__((ext_vector_type(4)));

#define HWSZ   262144     // 512*512
#define NE     12
#define NC     13         // 12 emb channels + 1 seg channel
#define NS     8
#define TROWS  16
#define TCOLS  128
#define NBLK   512        // 4 batches x 32 row-tiles x 4 col-tiles
#define HROWS  44         // rows r0-28 .. r0+15
#define HCOLS  156        // cols c0-28 .. c0+127
#define HSZ    (HROWS * HCOLS)   // 6864 floats
#define NCHUNK (HCOLS / 4)       // 39 f4-chunks per halo row
#define NSLOT  (HSZ / 4)         // 1716 f4 slots

__global__ __launch_bounds__(512) void affloss_main(
    const float* __restrict__ emb, const int* __restrict__ seg,
    const int* __restrict__ offs, float* __restrict__ partial) {
  __shared__ f4 buf4[NSLOT];            // 27,456 B halo buffer
  __shared__ float red[8][16];
  float* buf = (float*)buf4;

  // XCD swizzle (bijective, 512 % 8 == 0): contiguous tile band per XCD so
  // neighbor-tile halo overlap hits that XCD's L2.
  const int bid = blockIdx.x;
  const int nb  = (bid & 7) * (NBLK / 8) + (bid >> 3);
  const int b   = nb >> 7;              // batch 0..3
  const int rem = nb & 127;             // 32 row-tiles x 4 col-tiles
  const int r0  = (rem >> 2) * TROWS;   // 0..496
  const int c0  = (rem & 3) * TCOLS;    // 0..384

  const int tid = threadIdx.x;
  const int tx  = tid & 63;             // f2 col: tile cols 2tx, 2tx+1
  const int wv  = tid >> 6;             // wave 0..7 -> tile rows wv, wv+8

  const float* embB = emb + (size_t)b * NE * HWSZ;
  const int*   segB = seg + (size_t)b * HWSZ;

  int oyv[NS], oxv[NS];
  #pragma unroll
  for (int s = 0; s < NS; ++s) { oyv[s] = offs[2 * s]; oxv[s] = offs[2 * s + 1]; }

  // Per-thread staging geometry: slots tid, tid+512, tid+1024, tid+1536.
  // slot -> halo (row, 4-col chunk); global row clamps at 0 (replication);
  // negative col chunk (c0==0, cols<28) is entirely col<0 -> splat col 0.
  int srow[4], sgc[4];
  #pragma unroll
  for (int k = 0; k < 4; ++k) {
    const int slot = tid + k * 512;
    const int rr = slot / NCHUNK;
    const int ch = slot - rr * NCHUNK;
    int gr = r0 - 28 + rr; gr = gr < 0 ? 0 : gr;
    srow[k] = gr;
    sgc[k] = c0 - 28 + 4 * ch;
  }
  const bool s3 = tid < (NSLOT - 3 * 512);   // 180 threads own a 4th slot

  auto stage_load = [&](int e, f4* r) {
    const float* p = (e < NE) ? (embB + (size_t)e * HWSZ) : (const float*)segB;
    #pragma unroll
    for (int k = 0; k < 4; ++k) {
      if (k == 3 && !s3) continue;
      const float* rowp = p + srow[k] * 512;
      if (sgc[k] >= 0) {
        r[k] = *reinterpret_cast<const f4*>(rowp + sgc[k]);   // 16B aligned
      } else {
        const float v = rowp[0];                              // replication splat
        r[k] = f4{v, v, v, v};
      }
    }
  };
  auto stage_write = [&](const f4* r) {
    #pragma unroll
    for (int k = 0; k < 4; ++k) {
      if (k == 3 && !s3) continue;
      buf4[tid + k * 512] = r[k];                             // ds_write_b128
    }
  };

  f2 ssv[2][NS];
  #pragma unroll
  for (int q = 0; q < 2; ++q)
    #pragma unroll
    for (int s = 0; s < NS; ++s) ssv[q][s] = f2{0.f, 0.f};
  float numa[NS], dena[NS];
  #pragma unroll
  for (int s = 0; s < NS; ++s) { numa[s] = 0.f; dena[s] = 0.f; }

  f4 r[4];
  stage_load(0, r);

  for (int e = 0; e < NC; ++e) {
    __syncthreads();                   // readers of buf (channel e-1) done
    stage_write(r);                    // waits only on r's loads (vmcnt)
    __syncthreads();                   // writes visible; nothing in vm queue
    if (e + 1 < NC) stage_load(e + 1, r);   // flies during compute below

    if (e < NE) {
      #pragma unroll
      for (int q = 0; q < 2; ++q) {
        const int hr = wv + 8 * q + 28;           // halo row 28..43
        const int cb = hr * HCOLS + 28 + 2 * tx;  // center px0 idx (8B aligned)
        const f2 cc = *reinterpret_cast<const f2*>(&buf[cb]);
        #pragma unroll
        for (int s = 0; s < NS; ++s) {
          const int a = cb + oyv[s] * HCOLS + oxv[s];   // in-halo by constr.
          f2 sh; sh[0] = buf[a]; sh[1] = buf[a + 1];    // ds_read2_b32
          const f2 d = cc - sh;
          ssv[q][s][0] = fmaf(d[0], d[0], ssv[q][s][0]);
          ssv[q][s][1] = fmaf(d[1], d[1], ssv[q][s][1]);
        }
      }
    } else {
      // seg channel: bit-exact int compare + dice accumulation
      #pragma unroll
      for (int q = 0; q < 2; ++q) {
        const int hr = wv + 8 * q + 28;
        const int cb = hr * HCOLS + 28 + 2 * tx;
        const int tc0 = __float_as_int(buf[cb]);
        const int tc1 = __float_as_int(buf[cb + 1]);
        #pragma unroll
        for (int s = 0; s < NS; ++s) {
          const int a = cb + oyv[s] * HCOLS + oxv[s];
          const int t0 = __float_as_int(buf[a]);
          const int t1 = __float_as_int(buf[a + 1]);
          {
            const float n  = __builtin_amdgcn_sqrtf(ssv[q][s][0]);
            const float rc = fmaxf(fmaf(n, -(1.0f / 3.0f), 1.0f), 0.0f);
            const float A  = fmaf(-rc, rc, 1.0f);
            const float ta = (tc0 == t0) ? 0.f : 1.f;
            numa[s] = fmaf(A, ta, numa[s]);
            dena[s] += fmaf(A, A, ta);
          }
          {
            const float n  = __builtin_amdgcn_sqrtf(ssv[q][s][1]);
            const float rc = fmaxf(fmaf(n, -(1.0f / 3.0f), 1.0f), 0.0f);
            const float A  = fmaf(-rc, rc, 1.0f);
            const float ta = (tc1 == t1) ? 0.f : 1.f;
            numa[s] = fmaf(A, ta, numa[s]);
            dena[s] += fmaf(A, A, ta);
          }
        }
      }
    }
  }

  // block reduction: [0..7]=num, [8..15]=den
  float arr[16];
  #pragma unroll
  for (int s = 0; s < NS; ++s) { arr[s] = numa[s]; arr[8 + s] = dena[s]; }
  #pragma unroll
  for (int k = 0; k < 16; ++k) {
    float v = arr[k];
    #pragma unroll
    for (int o = 32; o > 0; o >>= 1) v += __shfl_down(v, o, 64);
    arr[k] = v;
  }
  const int lane = tid & 63;
  if (lane == 0) {
    #pragma unroll
    for (int k = 0; k < 16; ++k) red[wv][k] = arr[k];
  }
  __syncthreads();
  if (tid < 16) {
    float v = 0.f;
    #pragma unroll
    for (int w = 0; w < 8; ++w) v += red[w][tid];
    partial[tid * NBLK + blockIdx.x] = v;   // [channel][block]
  }
}

__global__ __launch_bounds__(1024) void affloss_final(
    const float* __restrict__ partial, float* __restrict__ out) {
  __shared__ double csum[16];
  const int lane = threadIdx.x & 63, wv = threadIdx.x >> 6;  // wv = channel

  double s = 0.0;
  for (int i = lane; i < NBLK; i += 64)
    s += (double)partial[wv * NBLK + i];
  #pragma unroll
  for (int o = 32; o > 0; o >>= 1) s += __shfl_down(s, o, 64);
  if (lane == 0) csum[wv] = s;
  __syncthreads();

  if (threadIdx.x == 0) {
    double total = 0.0;
    #pragma unroll
    for (int c = 0; c < 8; ++c) {
      double num = csum[c];
      double den = csum[8 + c];
      if (den < 1e-7) den = 1e-7;            // maximum(den, EPS)
      total += 1.0 - 2.0 * num / den;
    }
    out[0] = (float)total;
  }
}

extern "C" void kernel_launch(void* const* d_in, const int* in_sizes, int n_in,
                              void* d_out, int out_size, void* d_ws, size_t ws_size,
                              hipStream_t stream) {
  const float* emb  = (const float*)d_in[0];
  const int*   seg  = (const int*)d_in[1];
  const int*   offs = (const int*)d_in[2];
  float* partial = (float*)d_ws;   // 16*512 floats = 32,768 B

  affloss_main<<<NBLK, 512, 0, stream>>>(emb, seg, offs, partial);
  affloss_final<<<1, 1024, 0, stream>>>(partial, (float*)d_out);
}